// Round 1
// baseline (66.260 us; speedup 1.0000x reference)
//
#include <hip/hip_runtime.h>

// Problem constants
#define NP     64      // params per cell
#define NC     2080    // NP*(NP+1)/2 combinations
#define NCELLS 4096    // 64*64 grid cells
#define NB     32      // batch

#define CELLS_PER_BLOCK 4
#define BLOCKS 1024            // NCELLS / CELLS_PER_BLOCK

// Accumulate combos [C0, C1) of the triu(i<=j) row-major enumeration.
// Fully unrolled so p[] is register-indexed with literals only (no scratch).
template <int C0, int C1>
__device__ __forceinline__ float accum_range(const float* __restrict__ cf,
                                             const float (&p)[NP]) {
  float acc = 0.f;
  int c = 0;
#pragma unroll
  for (int i = 0; i < NP; ++i) {
#pragma unroll
    for (int j = i; j < NP; ++j) {
      if (c >= C0 && c < C1) {
        acc = fmaf(cf[c], p[i] * p[j], acc);
      }
      ++c;
    }
  }
  return acc;
}

__global__ __launch_bounds__(256, 4) void poly_cells_kernel(
    const float* __restrict__ param,   // [NB][NCELLS][NP]
    const float* __restrict__ coeffs,  // [NCELLS][NC]
    float* __restrict__ ws) {          // [BLOCKS][NB] partials
  __shared__ float scoef[CELLS_PER_BLOCK * NC];  // 33.3 KB
  __shared__ float sred[4][NB];

  const int tid = threadIdx.x;
  const int cellbase = blockIdx.x * CELLS_PER_BLOCK;

  // Stage 4 cells' coeffs (contiguous 8320 floats) into LDS, float4-coalesced.
  {
    const float4* gsrc =
        reinterpret_cast<const float4*>(coeffs + (size_t)cellbase * NC);
    float4* ldst = reinterpret_cast<float4*>(scoef);
#pragma unroll
    for (int k = 0; k < 9; ++k) {
      int idx = tid + k * 256;
      if (idx < (CELLS_PER_BLOCK * NC) / 4) ldst[idx] = gsrc[idx];
    }
  }
  __syncthreads();

  // Thread mapping: wave w (0..3), half h (0/1), lane b (0..31).
  // chunk = w&1 (wave-uniform), cell_local = ((w>>1)<<1)|h.
  const int b = tid & 31;
  const int h = (tid >> 5) & 1;
  const int w = tid >> 6;
  const int chunk = w & 1;
  const int cl = ((w >> 1) << 1) | h;
  const int cell = cellbase + cl;

  // Load this (b, cell)'s 64 params into registers (16x float4).
  float p[NP];
  {
    const float4* pp = reinterpret_cast<const float4*>(
        param + ((size_t)b * NCELLS + cell) * NP);
#pragma unroll
    for (int k = 0; k < NP / 4; ++k) {
      float4 v = pp[k];
      p[4 * k + 0] = v.x;
      p[4 * k + 1] = v.y;
      p[4 * k + 2] = v.z;
      p[4 * k + 3] = v.w;
    }
  }

  const float* cf = scoef + cl * NC;
  float acc = (chunk == 0) ? accum_range<0, 1040>(cf, p)
                           : accum_range<1040, 2080>(cf, p);

  // lane l and l^32: same b, different cell -> sum them.
  acc += __shfl_xor(acc, 32, 64);
  if (h == 0) sred[w][b] = acc;
  __syncthreads();

  if (tid < NB) {
    float s = sred[0][tid] + sred[1][tid] + sred[2][tid] + sred[3][tid];
    ws[(size_t)blockIdx.x * NB + tid] = s;
  }
}

// Sum ws[BLOCKS][NB] over blocks -> out[NB]. Single block, deterministic.
__global__ void poly_reduce_kernel(const float* __restrict__ ws,
                                   float* __restrict__ out) {
  __shared__ float sred[8][NB];
  const int tid = threadIdx.x;
  const int b = tid & 31;
  const int part = tid >> 5;  // 0..7
  float s = 0.f;
  for (int k = 0; k < BLOCKS / 8; ++k) {
    s += ws[(size_t)(part * (BLOCKS / 8) + k) * NB + b];
  }
  sred[part][b] = s;
  __syncthreads();
  if (tid < NB) {
    float t = 0.f;
#pragma unroll
    for (int q = 0; q < 8; ++q) t += sred[q][tid];
    out[tid] = t;
  }
}

extern "C" void kernel_launch(void* const* d_in, const int* in_sizes, int n_in,
                              void* d_out, int out_size, void* d_ws,
                              size_t ws_size, hipStream_t stream) {
  const float* param = (const float*)d_in[0];   // [32,64,64,64] f32
  const float* coeffs = (const float*)d_in[1];  // [64,64,2080] f32
  float* out = (float*)d_out;                   // [32] f32
  float* ws = (float*)d_ws;                     // BLOCKS*NB*4 = 128 KB

  hipLaunchKernelGGL(poly_cells_kernel, dim3(BLOCKS), dim3(256), 0, stream,
                     param, coeffs, ws);
  hipLaunchKernelGGL(poly_reduce_kernel, dim3(1), dim3(256), 0, stream, ws,
                     out);
}

// Round 2
// 40.062 us; speedup vs baseline: 1.6540x; 1.6540x over previous
//
#include <hip/hip_runtime.h>

// Problem constants
#define NP     64      // params per cell
#define NC     2080    // NP*(NP+1)/2 combinations
#define NCELLS 4096    // 64*64 grid cells
#define NB     32      // batch

#define CELLS_PER_BLOCK 4
#define BLOCKS (NCELLS / CELLS_PER_BLOCK)  // 1024

// Row split of the i<=j triangle: rows [0,19) = 1045 combos, rows [19,64) = 1035.
#define SPLIT_ROW 19
#define CBASE     1045   // combos preceding row 19 (19*64 - 19*18/2)

// Accumulate rows [I0, I1) of the triu(i<=j) row-major enumeration.
// cf must already point at the coefficient of combo (I0, I0).
// Plain nested loops, fully unrolled: every p[] index and cf offset is a
// compile-time constant (no filtered iterations -> no allocator blowup).
template <int I0, int I1>
__device__ __forceinline__ float accum_rows(const float* __restrict__ cf,
                                            const float (&p)[NP]) {
  float a0 = 0.f, a1 = 0.f, a2 = 0.f, a3 = 0.f;
  int c = 0;
#pragma unroll
  for (int i = I0; i < I1; ++i) {
#pragma unroll
    for (int j = i; j < NP; ++j) {
      float t = p[i] * p[j];
      if ((c & 3) == 0)      a0 = fmaf(cf[c], t, a0);
      else if ((c & 3) == 1) a1 = fmaf(cf[c], t, a1);
      else if ((c & 3) == 2) a2 = fmaf(cf[c], t, a2);
      else                   a3 = fmaf(cf[c], t, a3);
      ++c;
    }
  }
  return (a0 + a1) + (a2 + a3);
}

__global__ __launch_bounds__(256, 2) void poly_cells_kernel(
    const float* __restrict__ param,   // [NB][NCELLS][NP]
    const float* __restrict__ coeffs,  // [NCELLS][NC]
    float* __restrict__ ws) {          // [BLOCKS][NB] partials
  __shared__ float scoef[CELLS_PER_BLOCK * NC];  // 33.3 KB
  __shared__ float sred[4][NB];

  const int tid = threadIdx.x;
  const int cellbase = blockIdx.x * CELLS_PER_BLOCK;

  // Stage 4 cells' coeffs (contiguous 8320 floats) into LDS, float4-coalesced.
  {
    const float4* gsrc =
        reinterpret_cast<const float4*>(coeffs + (size_t)cellbase * NC);
    float4* ldst = reinterpret_cast<float4*>(scoef);
#pragma unroll
    for (int k = 0; k < 9; ++k) {
      int idx = tid + k * 256;
      if (idx < (CELLS_PER_BLOCK * NC) / 4) ldst[idx] = gsrc[idx];
    }
  }
  __syncthreads();

  // Thread mapping: wave w (0..3), half h (0/1), lane b (0..31).
  // chunk = w&1 (wave-uniform row-range), cell_local = ((w>>1)<<1)|h.
  const int b = tid & 31;
  const int h = (tid >> 5) & 1;
  const int w = tid >> 6;
  const int chunk = w & 1;
  const int cl = ((w >> 1) << 1) | h;
  const int cell = cellbase + cl;

  // Load this (b, cell)'s 64 params into registers (16x float4).
  float p[NP];
  {
    const float4* pp = reinterpret_cast<const float4*>(
        param + ((size_t)b * NCELLS + cell) * NP);
#pragma unroll
    for (int k = 0; k < NP / 4; ++k) {
      float4 v = pp[k];
      p[4 * k + 0] = v.x;
      p[4 * k + 1] = v.y;
      p[4 * k + 2] = v.z;
      p[4 * k + 3] = v.w;
    }
  }

  const float* cf = scoef + cl * NC;
  float acc = (chunk == 0) ? accum_rows<0, SPLIT_ROW>(cf, p)
                           : accum_rows<SPLIT_ROW, NP>(cf + CBASE, p);

  // lane l and l^32: same b, same chunk, the wave's two cells -> sum them.
  acc += __shfl_xor(acc, 32, 64);
  if (h == 0) sred[w][b] = acc;
  __syncthreads();

  if (tid < NB) {
    // waves 0,1 = cells {0,1} chunks {0,1}; waves 2,3 = cells {2,3}.
    float s = sred[0][tid] + sred[1][tid] + sred[2][tid] + sred[3][tid];
    ws[(size_t)blockIdx.x * NB + tid] = s;
  }
}

// Sum ws[BLOCKS][NB] over blocks -> out[NB]. Single block, deterministic.
__global__ void poly_reduce_kernel(const float* __restrict__ ws,
                                   float* __restrict__ out) {
  __shared__ float sred[8][NB];
  const int tid = threadIdx.x;
  const int b = tid & 31;
  const int part = tid >> 5;  // 0..7
  float s = 0.f;
  for (int k = 0; k < BLOCKS / 8; ++k) {
    s += ws[(size_t)(part * (BLOCKS / 8) + k) * NB + b];
  }
  sred[part][b] = s;
  __syncthreads();
  if (tid < NB) {
    float t = 0.f;
#pragma unroll
    for (int q = 0; q < 8; ++q) t += sred[q][tid];
    out[tid] = t;
  }
}

extern "C" void kernel_launch(void* const* d_in, const int* in_sizes, int n_in,
                              void* d_out, int out_size, void* d_ws,
                              size_t ws_size, hipStream_t stream) {
  const float* param = (const float*)d_in[0];   // [32,64,64,64] f32
  const float* coeffs = (const float*)d_in[1];  // [64,64,2080] f32
  float* out = (float*)d_out;                   // [32] f32
  float* ws = (float*)d_ws;                     // BLOCKS*NB*4 = 128 KB

  hipLaunchKernelGGL(poly_cells_kernel, dim3(BLOCKS), dim3(256), 0, stream,
                     param, coeffs, ws);
  hipLaunchKernelGGL(poly_reduce_kernel, dim3(1), dim3(256), 0, stream, ws,
                     out);
}

// Round 3
// 26.160 us; speedup vs baseline: 2.5329x; 1.5314x over previous
//
#include <hip/hip_runtime.h>

// Problem constants
#define NP     64      // params per cell
#define NC     2080    // NP*(NP+1)/2 packed upper-tri coefficients
#define NCELLS 4096    // 64*64 grid cells
#define NB     32      // batch
#define CELLS_PER_BLOCK 4
#define BLOCKS (NCELLS / CELLS_PER_BLOCK)  // 1024

typedef short bf16x8 __attribute__((ext_vector_type(8)));   // 8 bf16 (4 VGPRs)
typedef float f32x16 __attribute__((ext_vector_type(16)));  // MFMA accumulator

// f32 -> bf16 bits, round-to-nearest-even.
__device__ __forceinline__ short f2bf(float f) {
  unsigned u = __float_as_uint(f);
  u += 0x7fffu + ((u >> 16) & 1u);
  return (short)(u >> 16);
}

// One wave per cell. D = P(32b x 64i) * A(64i x 64j) upper-tri, then
// out[b] += sum_j Y[b,j] * P[b,j], accumulated across cells by a 2-stage
// deterministic reduction through ws.
__global__ __launch_bounds__(256, 2) void poly_mfma_kernel(
    const float* __restrict__ param,   // [NB][NCELLS][NP]
    const float* __restrict__ coeffs,  // [NCELLS][NC]
    float* __restrict__ ws) {          // [BLOCKS][NB]
  const int tid  = threadIdx.x;
  const int wave = tid >> 6;
  const int lane = tid & 63;
  const int lo5  = lane & 31;  // row b for A-op, col j for B-op/C
  const int hi   = lane >> 5;
  const int cell = blockIdx.x * CELLS_PER_BLOCK + wave;

  // ---- A-operand fragments: P rows. row b = lo5,
  //      k_i = ks*16 + 4*hi + (e&3) + 8*(e>>2)  (same k-map used for B).
  const float* pb = param + ((size_t)lo5 * NCELLS + cell) * NP;
  bf16x8 afrag[4];
#pragma unroll
  for (int ks = 0; ks < 4; ++ks) {
#pragma unroll
    for (int eh = 0; eh < 2; ++eh) {
      const int i0 = ks * 16 + 4 * hi + 8 * eh;
      const float4 v = *reinterpret_cast<const float4*>(pb + i0);
      afrag[ks][eh * 4 + 0] = f2bf(v.x);
      afrag[ks][eh * 4 + 1] = f2bf(v.y);
      afrag[ks][eh * 4 + 2] = f2bf(v.z);
      afrag[ks][eh * 4 + 3] = f2bf(v.w);
    }
  }

  // ---- B-operand gathers (upper-tri A_cell from packed coeffs) + MFMAs.
  // c(i,j) = i*(127-i)/2 + j  for i<=j; zero below the diagonal.
  const float* cb = coeffs + (size_t)cell * NC;
  f32x16 acc0, acc1;  // n-tiles j in [0,32) and [32,64)
#pragma unroll
  for (int r = 0; r < 16; ++r) { acc0[r] = 0.f; acc1[r] = 0.f; }

#pragma unroll
  for (int ks = 0; ks < 4; ++ks) {
    bf16x8 b0, b1;
#pragma unroll
    for (int e = 0; e < 8; ++e) {
      const int i = ks * 16 + 4 * hi + (e & 3) + 8 * (e >> 2);
      const int cbase = i * (127 - i) / 2;  // always in [0, NC-63]
      const float v0 = (lo5 >= i) ? cb[cbase + lo5] : 0.f;
      const float v1 = (lo5 + 32 >= i) ? cb[cbase + lo5 + 32] : 0.f;
      b0[e] = f2bf(v0);
      b1[e] = f2bf(v1);
    }
    acc0 = __builtin_amdgcn_mfma_f32_32x32x16_bf16(afrag[ks], b0, acc0, 0, 0, 0);
    acc1 = __builtin_amdgcn_mfma_f32_32x32x16_bf16(afrag[ks], b1, acc1, 0, 0, 0);
  }

  // ---- Epilogue: dacc[r] = sum over this lane's j of Y[b,j]*P[b,j].
  // C/D layout (HW-verified): col = lane&31, row b = (r&3)+8*(r>>2)+4*hi.
  float dacc[16];
#pragma unroll
  for (int r = 0; r < 16; ++r) {
    const int b = (r & 3) + 8 * (r >> 2) + 4 * hi;
    const float* pe = param + ((size_t)b * NCELLS + cell) * NP;
    dacc[r] = fmaf(acc0[r], pe[lo5], acc1[r] * pe[lo5 + 32]);
  }

  // ---- Reduce over j (lo5) within each 32-lane half.
#pragma unroll
  for (int r = 0; r < 16; ++r) {
    float v = dacc[r];
    v += __shfl_xor(v, 1, 64);
    v += __shfl_xor(v, 2, 64);
    v += __shfl_xor(v, 4, 64);
    v += __shfl_xor(v, 8, 64);
    v += __shfl_xor(v, 16, 64);
    dacc[r] = v;
  }

  __shared__ float sred[CELLS_PER_BLOCK][NB];
  if (lo5 == 0) {  // lanes 0 and 32: disjoint b sets (+0 / +4)
#pragma unroll
    for (int r = 0; r < 16; ++r) {
      const int b = (r & 3) + 8 * (r >> 2) + 4 * hi;
      sred[wave][b] = dacc[r];
    }
  }
  __syncthreads();
  if (tid < NB) {
    ws[(size_t)blockIdx.x * NB + tid] =
        sred[0][tid] + sred[1][tid] + sred[2][tid] + sred[3][tid];
  }
}

// Sum ws[BLOCKS][NB] over blocks -> out[NB]. Single block, deterministic.
__global__ void poly_reduce_kernel(const float* __restrict__ ws,
                                   float* __restrict__ out) {
  __shared__ float sred[8][NB];
  const int tid = threadIdx.x;
  const int b = tid & 31;
  const int part = tid >> 5;  // 0..7
  float s = 0.f;
  for (int k = 0; k < BLOCKS / 8; ++k) {
    s += ws[(size_t)(part * (BLOCKS / 8) + k) * NB + b];
  }
  sred[part][b] = s;
  __syncthreads();
  if (tid < NB) {
    float t = 0.f;
#pragma unroll
    for (int q = 0; q < 8; ++q) t += sred[q][tid];
    out[tid] = t;
  }
}

extern "C" void kernel_launch(void* const* d_in, const int* in_sizes, int n_in,
                              void* d_out, int out_size, void* d_ws,
                              size_t ws_size, hipStream_t stream) {
  const float* param = (const float*)d_in[0];   // [32,64,64,64] f32
  const float* coeffs = (const float*)d_in[1];  // [64,64,2080] f32
  float* out = (float*)d_out;                   // [32] f32
  float* ws = (float*)d_ws;                     // BLOCKS*NB*4 = 128 KB

  hipLaunchKernelGGL(poly_mfma_kernel, dim3(BLOCKS), dim3(256), 0, stream,
                     param, coeffs, ws);
  hipLaunchKernelGGL(poly_reduce_kernel, dim3(1), dim3(256), 0, stream, ws,
                     out);
}